// Round 2
// baseline (448.029 us; speedup 1.0000x reference)
//
#include <hip/hip_runtime.h>

typedef __attribute__((ext_vector_type(8))) short short8_t;
typedef __attribute__((ext_vector_type(4))) float f32x4;

#define MASK_VAL (-4294967295.0f)
#define NEG_BIG  (-1e30f)

__device__ __forceinline__ short f2bf(float x) {
    unsigned u;
    __builtin_memcpy(&u, &x, 4);
    u += 0x7FFFu + ((u >> 16) & 1u);   // round-to-nearest-even
    return (short)(u >> 16);
}
__device__ __forceinline__ float bf2f(short s) {
    unsigned u = ((unsigned)(unsigned short)s) << 16;
    float f;
    __builtin_memcpy(&f, &u, 4);
    return f;
}

// ---------------- prep: fold weights into d_ws (runs every call) ----------------
// ws layout (bytes):
//   0     : wkT  bf16 [64][64]  (W1b - W1c)^T   (row n, col k)
//   8192  : wdT  bf16 [64][64]  (W1d)^T
//   16384 : w2T  bf16 [32][64]  (W2)^T          (row o, col h)
//   20480 : wac  f32  [64][64]  W1a + W1c       (row i, col h)
__global__ void prep_fold(const float* __restrict__ W1, const float* __restrict__ W2,
                          void* __restrict__ ws)
{
    short* wkT = (short*)ws;
    short* wdT = wkT + 4096;
    short* w2T = wkT + 8192;
    float* wac = (float*)((char*)ws + 20480);
    const int tid = threadIdx.x;
    for (int idx = tid; idx < 4096; idx += 256) {
        int n = idx & 63, k = idx >> 6;
        float a  = W1[4096  + idx];   // W1b[k][n]
        float c  = W1[8192  + idx];   // W1c[k][n]
        float d  = W1[12288 + idx];   // W1d[k][n]
        wkT[n * 64 + k] = f2bf(a - c);
        wdT[n * 64 + k] = f2bf(d);
        wac[idx] = W1[idx] + c;       // elementwise: W1a + W1c (i-major)
    }
    for (int idx = tid; idx < 2048; idx += 256) {
        int o = idx & 31, h = idx >> 5;
        w2T[o * 64 + h] = f2bf(W2[idx]);   // W2[h][o], idx = h*32+o
    }
}

// ---------------- main: one WAVE per batch, online softmax, 1 barrier total ----
__global__ __launch_bounds__(256, 4) void attn_main(
    const float* __restrict__ query,    // (B,1,64)
    const float* __restrict__ keys,     // (B,200,64)
    const int*   __restrict__ keys_len, // (B,1)
    const float* __restrict__ b1,       // (64)
    const float* __restrict__ b2,       // (32)
    const float* __restrict__ W3,       // (32,1)
    const float* __restrict__ b3,       // (1)
    const void*  __restrict__ ws,
    float* __restrict__ out,            // (B,1,64)
    int B)
{
    constexpr int STR = 72;   // shorts; 144 B row stride -> 16B-aligned b128 everywhere
    const short* wkT = (const short*)ws;
    const short* wdT = wkT + 4096;
    const short* w2T = wkT + 8192;
    const float* wac = (const float*)((const char*)ws + 20480);

    __shared__ short Bk[64 * STR];      // (W1b-W1c)^T   (block-shared, staged once)
    __shared__ short Bd[64 * STR];      // W1d^T
    __shared__ short h1w[4][16 * STR];  // per-wave h1 tile (C-layout -> A-layout)
    __shared__ float qs[4][64];         // per-wave q
    __shared__ float csw[4][64];        // per-wave folded bias  b1 + q@(W1a+W1c)
    __shared__ float swv[4][16];        // per-wave per-tile scores

    const int tid  = threadIdx.x;
    const int lane = tid & 63;
    const int wid  = tid >> 6;
    const int col  = lane & 15;
    const int quad = lane >> 4;
    const int b    = blockIdx.x * 4 + wid;
    const bool act = (b < B);

    // ---- cooperative weight staging (all threads; once per block = per 4 batches) ----
    for (int c = tid; c < 512; c += 256) {
        int r = c >> 3, ch = (c & 7) * 8;
        *(short8_t*)&Bk[r * STR + ch] = *(const short8_t*)(wkT + r * 64 + ch);
        *(short8_t*)&Bd[r * STR + ch] = *(const short8_t*)(wdT + r * 64 + ch);
    }

    // ---- per-wave prologue (no cross-wave deps): q, tile-0 keys, params, cs ----
    const float* kb = nullptr;
    float4 n0, n1, n2, n3;
    float b2a = 0.f, b2b = 0.f, w3a = 0.f, w3b = 0.f, b3v = 0.f;
    short8_t w2f00, w2f01, w2f10, w2f11;
    if (act) {
        kb = keys + (size_t)b * 12800;
        if (lane < 16)
            ((float4*)&qs[wid][0])[lane] = ((const float4*)(query + (size_t)b * 64))[lane];
        {   // prefetch tile 0 (rows 0..15)
            const float* kr = kb + col * 64 + quad * 8;
            n0 = *(const float4*)(kr);
            n1 = *(const float4*)(kr + 4);
            n2 = *(const float4*)(kr + 32);
            n3 = *(const float4*)(kr + 36);
        }
        b2a = b2[col];      b2b = b2[col + 16];
        w3a = W3[col];      w3b = W3[col + 16];
        b3v = b3[0];
        // W2^T fragments live in registers for the whole kernel (L2-hot source)
        w2f00 = *(const short8_t*)(w2T + col * 64 + quad * 8);
        w2f01 = *(const short8_t*)(w2T + (16 + col) * 64 + quad * 8);
        w2f10 = *(const short8_t*)(w2T + col * 64 + 32 + quad * 8);
        w2f11 = *(const short8_t*)(w2T + (16 + col) * 64 + 32 + quad * 8);

        // cs[h] = b1[h] + sum_i q_i * (W1a+W1c)[i][h]   (lane h; wac reads coalesced, L2-hot)
        float acc = b1[lane];
#pragma unroll 16
        for (int i = 0; i < 64; ++i)
            acc += qs[wid][i] * wac[i * 64 + lane];
        csw[wid][lane] = acc;
    }
    __syncthreads();          // the ONLY block-wide barrier
    if (!act) return;

    const float4 qv0 = *(const float4*)&qs[wid][quad * 8];
    const float4 qv1 = *(const float4*)&qs[wid][quad * 8 + 4];
    const float4 qv2 = *(const float4*)&qs[wid][32 + quad * 8];
    const float4 qv3 = *(const float4*)&qs[wid][32 + quad * 8 + 4];

    const int len = keys_len[b];
    short* hw = h1w[wid];

    float m_run = NEG_BIG, l_run = 0.f;
    float accv[16];
#pragma unroll
    for (int i = 0; i < 16; ++i) accv[i] = 0.f;

    // ---- 13 tiles of 16 rows; fully independent per wave ----
    for (int jt = 0; jt < 13; ++jt) {
        float4 k0 = n0, k1 = n1, k2 = n2, k3 = n3;
        if (jt < 12) {        // prefetch next tile's rows (clamped)
            int row = jt * 16 + 16 + col;
            row = row < 200 ? row : 199;
            const float* kr = kb + row * 64 + quad * 8;
            n0 = *(const float4*)(kr);
            n1 = *(const float4*)(kr + 4);
            n2 = *(const float4*)(kr + 32);
            n3 = *(const float4*)(kr + 36);
        }

        short8_t aK0, aK1, aQ0, aQ1;
        aK0[0] = f2bf(k0.x); aK0[1] = f2bf(k0.y); aK0[2] = f2bf(k0.z); aK0[3] = f2bf(k0.w);
        aK0[4] = f2bf(k1.x); aK0[5] = f2bf(k1.y); aK0[6] = f2bf(k1.z); aK0[7] = f2bf(k1.w);
        aK1[0] = f2bf(k2.x); aK1[1] = f2bf(k2.y); aK1[2] = f2bf(k2.z); aK1[3] = f2bf(k2.w);
        aK1[4] = f2bf(k3.x); aK1[5] = f2bf(k3.y); aK1[6] = f2bf(k3.z); aK1[7] = f2bf(k3.w);
        aQ0[0] = f2bf(k0.x * qv0.x); aQ0[1] = f2bf(k0.y * qv0.y);
        aQ0[2] = f2bf(k0.z * qv0.z); aQ0[3] = f2bf(k0.w * qv0.w);
        aQ0[4] = f2bf(k1.x * qv1.x); aQ0[5] = f2bf(k1.y * qv1.y);
        aQ0[6] = f2bf(k1.z * qv1.z); aQ0[7] = f2bf(k1.w * qv1.w);
        aQ1[0] = f2bf(k2.x * qv2.x); aQ1[1] = f2bf(k2.y * qv2.y);
        aQ1[2] = f2bf(k2.z * qv2.z); aQ1[3] = f2bf(k2.w * qv2.w);
        aQ1[4] = f2bf(k3.x * qv3.x); aQ1[5] = f2bf(k3.y * qv3.y);
        aQ1[6] = f2bf(k3.z * qv3.z); aQ1[7] = f2bf(k3.w * qv3.w);

        f32x4 acc[4] = {f32x4{0,0,0,0}, f32x4{0,0,0,0}, f32x4{0,0,0,0}, f32x4{0,0,0,0}};
#pragma unroll
        for (int nt = 0; nt < 4; ++nt) {
            const short* bp = &Bk[(nt * 16 + col) * STR + quad * 8];
            const short* dp = &Bd[(nt * 16 + col) * STR + quad * 8];
            acc[nt] = __builtin_amdgcn_mfma_f32_16x16x32_bf16(aK0, *(const short8_t*)bp,        acc[nt], 0, 0, 0);
            acc[nt] = __builtin_amdgcn_mfma_f32_16x16x32_bf16(aK1, *(const short8_t*)(bp + 32), acc[nt], 0, 0, 0);
            acc[nt] = __builtin_amdgcn_mfma_f32_16x16x32_bf16(aQ0, *(const short8_t*)dp,        acc[nt], 0, 0, 0);
            acc[nt] = __builtin_amdgcn_mfma_f32_16x16x32_bf16(aQ1, *(const short8_t*)(dp + 32), acc[nt], 0, 0, 0);
        }

        // relu + cs -> per-wave h1 tile (intra-wave LDS, program-order safe)
#pragma unroll
        for (int nt = 0; nt < 4; ++nt) {
            float cadd = csw[wid][nt * 16 + col];
#pragma unroll
            for (int r = 0; r < 4; ++r)
                hw[(quad * 4 + r) * STR + nt * 16 + col] = f2bf(fmaxf(acc[nt][r] + cadd, 0.f));
        }

        // GEMM2 (K=64) with register-resident W2 fragments
        f32x4 acc2a = f32x4{0,0,0,0}, acc2b = f32x4{0,0,0,0};
        {
            short8_t a20 = *(const short8_t*)&hw[col * STR + quad * 8];
            acc2a = __builtin_amdgcn_mfma_f32_16x16x32_bf16(a20, w2f00, acc2a, 0, 0, 0);
            acc2b = __builtin_amdgcn_mfma_f32_16x16x32_bf16(a20, w2f01, acc2b, 0, 0, 0);
            short8_t a21 = *(const short8_t*)&hw[col * STR + 32 + quad * 8];
            acc2a = __builtin_amdgcn_mfma_f32_16x16x32_bf16(a21, w2f10, acc2a, 0, 0, 0);
            acc2b = __builtin_amdgcn_mfma_f32_16x16x32_bf16(a21, w2f11, acc2b, 0, 0, 0);
        }

        // fused b2/relu/W3/b3 -> tile scores (to per-wave LDS for the col-indexed read)
#pragma unroll
        for (int r = 0; r < 4; ++r) {
            float v = fmaxf(acc2a[r] + b2a, 0.f) * w3a
                    + fmaxf(acc2b[r] + b2b, 0.f) * w3b;
            v += __shfl_xor(v, 1);
            v += __shfl_xor(v, 2);
            v += __shfl_xor(v, 4);
            v += __shfl_xor(v, 8);
            if (col == 0) swv[wid][quad * 4 + r] = v + b3v;
        }
        float sv = swv[wid][col];              // score for row jt*16+col (all quads identical)

        // ---- online softmax update ----
        int  row  = jt * 16 + col;
        bool vrow = row < 200;
        sv = (row < len) ? sv : MASK_VAL;      // mask (len==0 -> uniform, matches reference)
        float svm = vrow ? sv : NEG_BIG;
        svm = fmaxf(svm, __shfl_xor(svm, 1));
        svm = fmaxf(svm, __shfl_xor(svm, 2));
        svm = fmaxf(svm, __shfl_xor(svm, 4));
        svm = fmaxf(svm, __shfl_xor(svm, 8));
        float m_new = fmaxf(m_run, svm);
        float p = vrow ? __expf(sv - m_new) : 0.f;
        float ps = p;
        ps += __shfl_xor(ps, 1);
        ps += __shfl_xor(ps, 2);
        ps += __shfl_xor(ps, 4);
        ps += __shfl_xor(ps, 8);
        if (m_new > m_run) {                   // wave-uniform; rescale only when max grows
            float scale = __expf(m_run - m_new);
            l_run *= scale;
#pragma unroll
            for (int i = 0; i < 16; ++i) accv[i] *= scale;
            m_run = m_new;
        }
        l_run += ps;
        // weighted-key accumulation from the tile's register fragments (keys read ONCE)
#pragma unroll
        for (int i = 0; i < 8; ++i) {
            accv[i]     += p * bf2f(aK0[i]);
            accv[8 + i] += p * bf2f(aK1[i]);
        }
    }

    // ---- epilogue: cross-col reduce + normalize + store ----
    float inv = 1.f / l_run;
#pragma unroll
    for (int i = 0; i < 16; ++i) {
        float v = accv[i];
        v += __shfl_xor(v, 1);
        v += __shfl_xor(v, 2);
        v += __shfl_xor(v, 4);
        v += __shfl_xor(v, 8);
        accv[i] = v * inv;
    }
    if (col == 0) {
        float* op = out + (size_t)b * 64;
        *(float4*)(op + quad * 8)          = make_float4(accv[0],  accv[1],  accv[2],  accv[3]);
        *(float4*)(op + quad * 8 + 4)      = make_float4(accv[4],  accv[5],  accv[6],  accv[7]);
        *(float4*)(op + 32 + quad * 8)     = make_float4(accv[8],  accv[9],  accv[10], accv[11]);
        *(float4*)(op + 32 + quad * 8 + 4) = make_float4(accv[12], accv[13], accv[14], accv[15]);
    }
}

extern "C" void kernel_launch(void* const* d_in, const int* in_sizes, int n_in,
                              void* d_out, int out_size, void* d_ws, size_t ws_size,
                              hipStream_t stream) {
    const float* query    = (const float*)d_in[0];
    const float* keys     = (const float*)d_in[1];
    const int*   keys_len = (const int*)d_in[2];
    const float* W1       = (const float*)d_in[3];
    const float* b1       = (const float*)d_in[4];
    const float* W2       = (const float*)d_in[5];
    const float* b2       = (const float*)d_in[6];
    const float* W3       = (const float*)d_in[7];
    const float* b3       = (const float*)d_in[8];
    float* out            = (float*)d_out;

    const int B = in_sizes[1] / 12800;   // keys is (B,200,64)

    prep_fold<<<dim3(1), dim3(256), 0, stream>>>(W1, W2, d_ws);
    attn_main<<<dim3((B + 3) / 4), dim3(256), 0, stream>>>(
        query, keys, keys_len, b1, b2, W3, b3, d_ws, out, B);
}

// Round 3
// 327.841 us; speedup vs baseline: 1.3666x; 1.3666x over previous
//
#include <hip/hip_runtime.h>

typedef __attribute__((ext_vector_type(8))) short short8_t;
typedef __attribute__((ext_vector_type(4))) float f32x4;

#define MASK_VAL (-4294967295.0f)
#define NEG_BIG  (-1e30f)

__device__ __forceinline__ short f2bf(float x) {
    unsigned u;
    __builtin_memcpy(&u, &x, 4);
    u += 0x7FFFu + ((u >> 16) & 1u);   // round-to-nearest-even
    return (short)(u >> 16);
}
__device__ __forceinline__ float bf2f(short s) {
    unsigned u = ((unsigned)(unsigned short)s) << 16;
    float f;
    __builtin_memcpy(&f, &u, 4);
    return f;
}

// ---------------- prep 1: fold weights into d_ws ----------------
// ws layout (bytes):
//   0     : wkT   bf16 [64][64]  (W1b - W1c)^T   (row n, col k)
//   8192  : wdT   bf16 [64][64]  (W1d)^T
//   16384 : w2T   bf16 [32][64]  (W2)^T          (row o, col h)
//   20480 : wac   f32  [64][64]  W1a + W1c       (row i, col h)
//   36864 : csAll f32  [B][64]   b1 + q_b @ (W1a+W1c)
__global__ void prep_fold(const float* __restrict__ W1, const float* __restrict__ W2,
                          void* __restrict__ ws)
{
    short* wkT = (short*)ws;
    short* wdT = wkT + 4096;
    short* w2T = wkT + 8192;
    float* wac = (float*)((char*)ws + 20480);
    const int tid = threadIdx.x;
    for (int idx = tid; idx < 4096; idx += 256) {
        int n = idx & 63, k = idx >> 6;
        float a  = W1[4096  + idx];   // W1b[k][n]
        float c  = W1[8192  + idx];   // W1c[k][n]
        float d  = W1[12288 + idx];   // W1d[k][n]
        wkT[n * 64 + k] = f2bf(a - c);
        wdT[n * 64 + k] = f2bf(d);
        wac[idx] = W1[idx] + c;       // elementwise: W1a + W1c (i-major)
    }
    for (int idx = tid; idx < 2048; idx += 256) {
        int o = idx & 31, h = idx >> 5;
        w2T[o * 64 + h] = f2bf(W2[idx]);   // W2[h][o], idx = h*32+o
    }
}

// ---------------- prep 2: csAll[b][h] = b1[h] + sum_i q[b][i]*wac[i][h] ----------
// 16 batches per block; wac staged in LDS once per block (~5 MB total traffic).
__global__ __launch_bounds__(256) void prep_cs(
    const float* __restrict__ query, const float* __restrict__ b1,
    void* __restrict__ ws, int B)
{
    const float* wac = (const float*)((const char*)ws + 20480);
    float* csAll     = (float*)((char*)ws + 36864);
    __shared__ float wacs[4096];     // 16 KB
    __shared__ float qsb[16 * 64];   // 4 KB
    __shared__ float b1s[64];
    const int tid = threadIdx.x;
    const int g0  = blockIdx.x * 16;
    for (int i = tid; i < 1024; i += 256)
        ((float4*)wacs)[i] = ((const float4*)wac)[i];
    {
        int nb = B - g0; if (nb > 16) nb = 16;
        for (int i = tid; i < nb * 16; i += 256)
            ((float4*)qsb)[i] = ((const float4*)(query + (size_t)g0 * 64))[i];
    }
    if (tid < 64) b1s[tid] = b1[tid];
    __syncthreads();
    for (int o = tid; o < 1024; o += 256) {
        int bb = o >> 6, h = o & 63;
        if (g0 + bb >= B) continue;
        float acc = b1s[h];
#pragma unroll 16
        for (int i = 0; i < 64; ++i)
            acc += qsb[bb * 64 + i] * wacs[i * 64 + h];
        csAll[(size_t)(g0 + bb) * 64 + h] = acc;
    }
}

// ---------------- main: one WAVE per batch, online softmax, 1 barrier total ----
__global__ __launch_bounds__(256, 2) void attn_main(
    const float* __restrict__ query,    // (B,1,64)
    const float* __restrict__ keys,     // (B,200,64)
    const int*   __restrict__ keys_len, // (B,1)
    const float* __restrict__ b2,       // (32)
    const float* __restrict__ W3,       // (32,1)
    const float* __restrict__ b3,       // (1)
    const void*  __restrict__ ws,
    float* __restrict__ out,            // (B,1,64)
    int B)
{
    constexpr int STR = 72;   // shorts; 144 B row stride -> 16B-aligned b128 everywhere
    const short* wkT   = (const short*)ws;
    const short* wdT   = wkT + 4096;
    const short* w2T   = wkT + 8192;
    const float* csAll = (const float*)((const char*)ws + 36864);

    __shared__ short Bk[64 * STR];      // (W1b-W1c)^T   (block-shared, staged once)
    __shared__ short Bd[64 * STR];      // W1d^T
    __shared__ short W2s[32 * STR];     // W2^T
    __shared__ short h1w[4][16 * STR];  // per-wave h1 tile (C-layout -> A-layout)
    __shared__ float swv[4][16];        // per-wave per-tile scores

    const int tid  = threadIdx.x;
    const int lane = tid & 63;
    const int wid  = tid >> 6;
    const int col  = lane & 15;
    const int quad = lane >> 4;
    const int b    = blockIdx.x * 4 + wid;
    const bool act = (b < B);

    // ---- cooperative staging (all threads; once per block = per 4 batches) ----
    for (int c = tid; c < 512; c += 256) {
        int r = c >> 3, ch = (c & 7) * 8;
        *(short8_t*)&Bk[r * STR + ch] = *(const short8_t*)(wkT + r * 64 + ch);
        *(short8_t*)&Bd[r * STR + ch] = *(const short8_t*)(wdT + r * 64 + ch);
    }
    {
        int r = tid >> 3, ch = (tid & 7) * 8;
        *(short8_t*)&W2s[r * STR + ch] = *(const short8_t*)(w2T + r * 64 + ch);
    }

    // ---- per-wave prologue (no cross-wave deps) ----
    const float* kb = nullptr;
    float4 n0, n1, n2, n3;
    float4 qv0, qv1, qv2, qv3;
    float cs0 = 0.f, cs1 = 0.f, cs2 = 0.f, cs3 = 0.f;
    float b2a = 0.f, b2b = 0.f, w3a = 0.f, w3b = 0.f, b3v = 0.f;
    if (act) {
        kb = keys + (size_t)b * 12800;
        {   // prefetch tile 0 (rows 0..15)
            const float* kr = kb + col * 64 + quad * 8;
            n0 = *(const float4*)(kr);
            n1 = *(const float4*)(kr + 4);
            n2 = *(const float4*)(kr + 32);
            n3 = *(const float4*)(kr + 36);
        }
        const float* qb = query + (size_t)b * 64;
        qv0 = *(const float4*)(qb + quad * 8);
        qv1 = *(const float4*)(qb + quad * 8 + 4);
        qv2 = *(const float4*)(qb + 32 + quad * 8);
        qv3 = *(const float4*)(qb + 32 + quad * 8 + 4);
        const float* cb = csAll + (size_t)b * 64;
        cs0 = cb[col]; cs1 = cb[16 + col]; cs2 = cb[32 + col]; cs3 = cb[48 + col];
        b2a = b2[col];      b2b = b2[col + 16];
        w3a = W3[col];      w3b = W3[col + 16];
        b3v = b3[0];
    }
    __syncthreads();          // the ONLY block-wide barrier
    if (!act) return;

    const int len = keys_len[b];
    short* hw = h1w[wid];

    float m_run = NEG_BIG, l_run = 0.f;
    float accv[16];
#pragma unroll
    for (int i = 0; i < 16; ++i) accv[i] = 0.f;

    // ---- 13 tiles of 16 rows; fully independent per wave ----
    for (int jt = 0; jt < 13; ++jt) {
        float4 k0 = n0, k1 = n1, k2 = n2, k3 = n3;
        if (jt < 12) {        // prefetch next tile's rows (clamped)
            int row = jt * 16 + 16 + col;
            row = row < 200 ? row : 199;
            const float* kr = kb + row * 64 + quad * 8;
            n0 = *(const float4*)(kr);
            n1 = *(const float4*)(kr + 4);
            n2 = *(const float4*)(kr + 32);
            n3 = *(const float4*)(kr + 36);
        }

        short8_t aK0, aK1, aQ0, aQ1;
        aK0[0] = f2bf(k0.x); aK0[1] = f2bf(k0.y); aK0[2] = f2bf(k0.z); aK0[3] = f2bf(k0.w);
        aK0[4] = f2bf(k1.x); aK0[5] = f2bf(k1.y); aK0[6] = f2bf(k1.z); aK0[7] = f2bf(k1.w);
        aK1[0] = f2bf(k2.x); aK1[1] = f2bf(k2.y); aK1[2] = f2bf(k2.z); aK1[3] = f2bf(k2.w);
        aK1[4] = f2bf(k3.x); aK1[5] = f2bf(k3.y); aK1[6] = f2bf(k3.z); aK1[7] = f2bf(k3.w);
        aQ0[0] = f2bf(k0.x * qv0.x); aQ0[1] = f2bf(k0.y * qv0.y);
        aQ0[2] = f2bf(k0.z * qv0.z); aQ0[3] = f2bf(k0.w * qv0.w);
        aQ0[4] = f2bf(k1.x * qv1.x); aQ0[5] = f2bf(k1.y * qv1.y);
        aQ0[6] = f2bf(k1.z * qv1.z); aQ0[7] = f2bf(k1.w * qv1.w);
        aQ1[0] = f2bf(k2.x * qv2.x); aQ1[1] = f2bf(k2.y * qv2.y);
        aQ1[2] = f2bf(k2.z * qv2.z); aQ1[3] = f2bf(k2.w * qv2.w);
        aQ1[4] = f2bf(k3.x * qv3.x); aQ1[5] = f2bf(k3.y * qv3.y);
        aQ1[6] = f2bf(k3.z * qv3.z); aQ1[7] = f2bf(k3.w * qv3.w);

        f32x4 acc[4] = {f32x4{0,0,0,0}, f32x4{0,0,0,0}, f32x4{0,0,0,0}, f32x4{0,0,0,0}};
#pragma unroll
        for (int nt = 0; nt < 4; ++nt) {
            const short* bp = &Bk[(nt * 16 + col) * STR + quad * 8];
            const short* dp = &Bd[(nt * 16 + col) * STR + quad * 8];
            acc[nt] = __builtin_amdgcn_mfma_f32_16x16x32_bf16(aK0, *(const short8_t*)bp,        acc[nt], 0, 0, 0);
            acc[nt] = __builtin_amdgcn_mfma_f32_16x16x32_bf16(aK1, *(const short8_t*)(bp + 32), acc[nt], 0, 0, 0);
            acc[nt] = __builtin_amdgcn_mfma_f32_16x16x32_bf16(aQ0, *(const short8_t*)dp,        acc[nt], 0, 0, 0);
            acc[nt] = __builtin_amdgcn_mfma_f32_16x16x32_bf16(aQ1, *(const short8_t*)(dp + 32), acc[nt], 0, 0, 0);
        }

        // relu + cs -> per-wave h1 tile (intra-wave LDS, program-order safe)
        float csv[4] = {cs0, cs1, cs2, cs3};
#pragma unroll
        for (int nt = 0; nt < 4; ++nt) {
            float cadd = csv[nt];
#pragma unroll
            for (int r = 0; r < 4; ++r)
                hw[(quad * 4 + r) * STR + nt * 16 + col] = f2bf(fmaxf(acc[nt][r] + cadd, 0.f));
        }

        // GEMM2 (K=64) from the shared W2 LDS tile
        f32x4 acc2a = f32x4{0,0,0,0}, acc2b = f32x4{0,0,0,0};
#pragma unroll
        for (int ks = 0; ks < 2; ++ks) {
            short8_t a2 = *(const short8_t*)&hw[col * STR + ks * 32 + quad * 8];
            acc2a = __builtin_amdgcn_mfma_f32_16x16x32_bf16(
                a2, *(const short8_t*)&W2s[col * STR + ks * 32 + quad * 8], acc2a, 0, 0, 0);
            acc2b = __builtin_amdgcn_mfma_f32_16x16x32_bf16(
                a2, *(const short8_t*)&W2s[(16 + col) * STR + ks * 32 + quad * 8], acc2b, 0, 0, 0);
        }

        // fused b2/relu/W3/b3 -> tile scores (per-wave LDS bounce for col-indexed read)
#pragma unroll
        for (int r = 0; r < 4; ++r) {
            float v = fmaxf(acc2a[r] + b2a, 0.f) * w3a
                    + fmaxf(acc2b[r] + b2b, 0.f) * w3b;
            v += __shfl_xor(v, 1);
            v += __shfl_xor(v, 2);
            v += __shfl_xor(v, 4);
            v += __shfl_xor(v, 8);
            if (col == 0) swv[wid][quad * 4 + r] = v + b3v;
        }
        float sv = swv[wid][col];              // score for row jt*16+col (all quads identical)

        // ---- online softmax update ----
        int  row  = jt * 16 + col;
        bool vrow = row < 200;
        sv = (row < len) ? sv : MASK_VAL;      // mask (len==0 -> uniform, matches reference)
        float svm = vrow ? sv : NEG_BIG;
        svm = fmaxf(svm, __shfl_xor(svm, 1));
        svm = fmaxf(svm, __shfl_xor(svm, 2));
        svm = fmaxf(svm, __shfl_xor(svm, 4));
        svm = fmaxf(svm, __shfl_xor(svm, 8));
        float m_new = fmaxf(m_run, svm);
        float p = vrow ? __expf(sv - m_new) : 0.f;
        float ps = p;
        ps += __shfl_xor(ps, 1);
        ps += __shfl_xor(ps, 2);
        ps += __shfl_xor(ps, 4);
        ps += __shfl_xor(ps, 8);
        if (m_new > m_run) {                   // wave-uniform; rescale only when max grows
            float scale = __expf(m_run - m_new);
            l_run *= scale;
#pragma unroll
            for (int i = 0; i < 16; ++i) accv[i] *= scale;
            m_run = m_new;
        }
        l_run += ps;
        // weighted-key accumulation from the tile's register fragments (keys read ONCE)
#pragma unroll
        for (int i = 0; i < 8; ++i) {
            accv[i]     += p * bf2f(aK0[i]);
            accv[8 + i] += p * bf2f(aK1[i]);
        }
    }

    // ---- epilogue: cross-col reduce + normalize + store ----
    float inv = 1.f / l_run;
#pragma unroll
    for (int i = 0; i < 16; ++i) {
        float v = accv[i];
        v += __shfl_xor(v, 1);
        v += __shfl_xor(v, 2);
        v += __shfl_xor(v, 4);
        v += __shfl_xor(v, 8);
        accv[i] = v * inv;
    }
    if (col == 0) {
        float* op = out + (size_t)b * 64;
        *(float4*)(op + quad * 8)          = make_float4(accv[0],  accv[1],  accv[2],  accv[3]);
        *(float4*)(op + quad * 8 + 4)      = make_float4(accv[4],  accv[5],  accv[6],  accv[7]);
        *(float4*)(op + 32 + quad * 8)     = make_float4(accv[8],  accv[9],  accv[10], accv[11]);
        *(float4*)(op + 32 + quad * 8 + 4) = make_float4(accv[12], accv[13], accv[14], accv[15]);
    }
}

extern "C" void kernel_launch(void* const* d_in, const int* in_sizes, int n_in,
                              void* d_out, int out_size, void* d_ws, size_t ws_size,
                              hipStream_t stream) {
    const float* query    = (const float*)d_in[0];
    const float* keys     = (const float*)d_in[1];
    const int*   keys_len = (const int*)d_in[2];
    const float* W1       = (const float*)d_in[3];
    const float* b1       = (const float*)d_in[4];
    const float* W2       = (const float*)d_in[5];
    const float* b2       = (const float*)d_in[6];
    const float* W3       = (const float*)d_in[7];
    const float* b3       = (const float*)d_in[8];
    float* out            = (float*)d_out;

    const int B = in_sizes[1] / 12800;   // keys is (B,200,64)

    prep_fold<<<dim3(1), dim3(256), 0, stream>>>(W1, W2, d_ws);
    prep_cs<<<dim3((B + 15) / 16), dim3(256), 0, stream>>>(query, b1, d_ws, B);
    attn_main<<<dim3((B + 3) / 4), dim3(256), 0, stream>>>(
        query, keys, keys_len, b2, W3, b3, d_ws, out, B);
}